// Round 6
// baseline (53.103 us; speedup 1.0000x reference)
//
#include <hip/hip_runtime.h>

typedef unsigned short u16;
typedef __bf16 bf16x8 __attribute__((ext_vector_type(8)));
typedef float f32x4 __attribute__((ext_vector_type(4)));

#define B_   16
#define H_   56
#define W_   56
#define C_   128
#define OH_  54
#define OW_  54
#define NF_  256
#define KF_  1152           // C_*9
#define M_   46656          // B_*OH_*OW_
#define NNZ_ 58982

#define XB_ELEMS (B_*H_*W_*C_)       // 6422528
#define WT_ELEMS (36*4*256*8)        // 294912 (pre-tiled [kt][ks][col][8])

__device__ __forceinline__ u16 f2bf(float f) {
    unsigned u = __float_as_uint(f);
    u += 0x7FFFu + ((u >> 16) & 1u);
    return (u16)(u >> 16);
}

__device__ __forceinline__ void gload16(const void* g, void* l) {
    __builtin_amdgcn_global_load_lds(
        (const __attribute__((address_space(1))) unsigned int*)g,
        (__attribute__((address_space(3))) unsigned int*)l,
        16, 0, 0);
}

// ---- kernel 1: x f32 -> bf16 (8/thread) + fused zeroing of wt ----
__global__ __launch_bounds__(256) void cvt_x_kernel(const float* __restrict__ x,
                                                    u16* __restrict__ xb,
                                                    u16* __restrict__ wt) {
    // blocks 0..143 also zero the 576KB pre-tiled W image (144*256*16B exact)
    if (blockIdx.x < 144) {
        uint4 z = {0u, 0u, 0u, 0u};
        ((uint4*)wt)[blockIdx.x * 256 + threadIdx.x] = z;
    }
    int i = (blockIdx.x * 256 + threadIdx.x) * 8;
    float4 v0 = *(const float4*)(x + i);
    float4 v1 = *(const float4*)(x + i + 4);
    union { u16 u[8]; uint4 v; } r;
    r.u[0] = f2bf(v0.x); r.u[1] = f2bf(v0.y); r.u[2] = f2bf(v0.z); r.u[3] = f2bf(v0.w);
    r.u[4] = f2bf(v1.x); r.u[5] = f2bf(v1.y); r.u[6] = f2bf(v1.z); r.u[7] = f2bf(v1.w);
    *(uint4*)(xb + i) = r.v;
}

// ---- kernel 2: scatter sparse values into PRE-TILED W: [kt][ks][col][8] ----
__global__ __launch_bounds__(256) void scatter_kernel(const float* __restrict__ kv,
                                                      const int* __restrict__ idx,
                                                      u16* __restrict__ wt) {
    int t = blockIdx.x * 256 + threadIdx.x;
    if (t >= NNZ_) return;
    int k   = idx[2*t];      // row in [0,1152)
    int col = idx[2*t + 1];  // col in [0,256)
    int kt = k >> 5, ks = (k >> 3) & 3, e = k & 7;
    wt[(kt * 4 + ks) * 2048 + col * 8 + e] = f2bf(kv[t]);
}

// ---- kernel 3: implicit-GEMM conv, BM=96, 6 waves, counted vmcnt ----
// 486 blocks (exact), BN=256, BK=32. Wave tile 32x128 (wr=wid>>1, wc=wid&1).
// Staging: waves 0-3 stage B (4 gloads/thread), waves 4-5 stage A (3 gloads,
// rows u>>2 + {0,32,64}; kc-XOR source swizzle identical across the 3 rows).
// 2-deep dbuf, per-wave counted vmcnt(4)/(3) — never drains to 0 mid-loop.
__global__ __launch_bounds__(384) void spconv_gemm(const u16* __restrict__ xb,
                                                   const u16* __restrict__ wt,
                                                   const float* __restrict__ bias,
                                                   float* __restrict__ out) {
    __shared__ __align__(16) u16 As[2][96 * 32];      // 2 x 6 KB
    __shared__ __align__(16) u16 Bs[2][4 * 256 * 8];  // 2 x 16 KB

    const int t    = threadIdx.x;
    const int lane = t & 63;
    const int wid  = t >> 6;

    // bijective XCD swizzle (nwg=486 -> m204 formula)
    const int nwg = gridDim.x;
    const int q = nwg >> 3, r = nwg & 7;
    const int xcd = blockIdx.x & 7, inner = blockIdx.x >> 3;
    const int wg = (xcd < r ? xcd * (q + 1) : r * (q + 1) + (xcd - r) * q) + inner;
    const int m0 = wg * 96;

    // A staging geometry (used by waves 4-5): thread u = t&127 stages cells
    // u, u+128, u+256 -> rows u>>2 + {0,32,64}, kc = u&3. 64B sectors/row.
    const int u     = t & 127;
    const int arow0 = u >> 2;
    const int kc    = u & 3;
    const int kcs   = kc ^ (arow0 & 3) ^ ((arow0 >> 2) & 3);  // same for +32,+64
    const int kco   = kcs * 8;
    const int a_dst0 = u * 8;

    const u16* a_base0;
    const u16* a_base1;
    const u16* a_base2;
    {
        int mg0 = m0 + arow0;
#define MKBASE(dst, mg) do {                                   \
        int bb_  = (mg) / (OH_ * OW_);                         \
        int rem_ = (mg) % (OH_ * OW_);                         \
        int ii_  = rem_ / OW_;                                 \
        int jj_  = rem_ % OW_;                                 \
        dst = xb + ((bb_ * H_ + ii_) * W_ + jj_) * C_;         \
    } while (0)
        MKBASE(a_base0, mg0);
        MKBASE(a_base1, mg0 + 32);
        MKBASE(a_base2, mg0 + 64);
#undef MKBASE
    }

    f32x4 acc[2][8];
    const f32x4 zz = {0.f, 0.f, 0.f, 0.f};
#pragma unroll
    for (int i = 0; i < 2; ++i)
#pragma unroll
        for (int j = 0; j < 8; ++j) acc[i][j] = zz;

    const int ks  = lane >> 4;
    const int r16 = lane & 15;
    const int cidx = ks ^ (r16 & 3) ^ ((r16 >> 2) & 3);
    const int wr = wid >> 1;          // 0..2  (M sub-block of 32)
    const int wc = wid & 1;           // 0..1  (N half of 128)

#define ISSUE(kn, bi) do {                                                  \
    if (t < 256) {                                                          \
        const u16* bsrc_ = wt + (kn) * 8192 + t * 8;                        \
        gload16(bsrc_,        &Bs[bi][0] + t * 8);                          \
        gload16(bsrc_ + 2048, &Bs[bi][0] + t * 8 + 2048);                   \
        gload16(bsrc_ + 4096, &Bs[bi][0] + t * 8 + 4096);                   \
        gload16(bsrc_ + 6144, &Bs[bi][0] + t * 8 + 6144);                   \
    } else {                                                                \
        int g_  = (kn) >> 2;                                                \
        int di_ = (g_ * 11) >> 5;                                           \
        int dj_ = g_ - 3 * di_;                                             \
        int aoff_ = (di_ * W_ + dj_) * C_ + ((kn) & 3) * 32 + kco;          \
        gload16(a_base0 + aoff_, &As[bi][0] + a_dst0);                      \
        gload16(a_base1 + aoff_, &As[bi][0] + a_dst0 + 1024);               \
        gload16(a_base2 + aoff_, &As[bi][0] + a_dst0 + 2048);               \
    }                                                                       \
} while (0)

#define COMPUTE(bi) do {                                                    \
    bf16x8 a0_ = *(const bf16x8*)(&As[bi][(wr * 32 + r16) * 32 + cidx * 8]);\
    bf16x8 a1_ = *(const bf16x8*)(&As[bi][(wr * 32 + 16 + r16) * 32 + cidx * 8]); \
    _Pragma("unroll")                                                       \
    for (int nf = 0; nf < 8; ++nf) {                                        \
        bf16x8 b_ = *(const bf16x8*)(&Bs[bi][(ks * 256 + wc * 128 + nf * 16 + r16) * 8]); \
        acc[0][nf] = __builtin_amdgcn_mfma_f32_16x16x32_bf16(a0_, b_, acc[0][nf], 0, 0, 0); \
        acc[1][nf] = __builtin_amdgcn_mfma_f32_16x16x32_bf16(a1_, b_, acc[1][nf], 0, 0, 0); \
    }                                                                       \
} while (0)

// per-wave counted waits (B-stagers have 4 loads/tile in flight, A-stagers 3)
#define WAITVM(nb, na) do {                                                 \
    if (wid < 4) { asm volatile("s_waitcnt vmcnt(" #nb ")" ::: "memory"); } \
    else         { asm volatile("s_waitcnt vmcnt(" #na ")" ::: "memory"); } \
} while (0)
#define BAR() do { __builtin_amdgcn_s_barrier();                            \
                   asm volatile("" ::: "memory"); } while (0)

    // prologue: 2 tiles in flight
    ISSUE(0, 0);
    ISSUE(1, 1);

    // main loop: iters 0..33 issue tiles 2..35; vmcnt never drains to 0
#pragma unroll
    for (int k = 0; k < 34; ++k) {
        WAITVM(4, 3);         // tile k landed; tile k+1 stays in flight
        BAR();                // all waves' tile-k staging visible
        COMPUTE(k & 1);
        BAR();                // all waves done reading buf[k&1]
        ISSUE(k + 2, k & 1);
    }
    // tail: iters 34, 35
    WAITVM(4, 3); BAR(); COMPUTE(0); BAR();
    WAITVM(0, 0); BAR(); COMPUTE(1);

#undef ISSUE
#undef COMPUTE
#undef WAITVM
#undef BAR

    // epilogue: C/D layout col = lane&15, row = (lane>>4)*4 + reg (m89-verified)
    const int rgrp = lane >> 4;
#pragma unroll
    for (int nf = 0; nf < 8; ++nf) {
        int col  = wc * 128 + nf * 16 + r16;
        float bv = bias[col];
#pragma unroll
        for (int mf = 0; mf < 2; ++mf) {
#pragma unroll
            for (int rr = 0; rr < 4; ++rr) {
                int row = m0 + wr * 32 + mf * 16 + rgrp * 4 + rr;
                float v = acc[mf][nf][rr] + bv;
                out[row * NF_ + col] = fmaxf(v, 0.f);
            }
        }
    }
}

extern "C" void kernel_launch(void* const* d_in, const int* in_sizes, int n_in,
                              void* d_out, int out_size, void* d_ws, size_t ws_size,
                              hipStream_t stream) {
    const float* x    = (const float*)d_in[0];
    const float* kv   = (const float*)d_in[1];
    const float* bias = (const float*)d_in[2];
    const int*   idx  = (const int*)d_in[3];
    float* out = (float*)d_out;

    u16* xb  = (u16*)d_ws;
    u16* wtp = (u16*)((char*)d_ws + (size_t)XB_ELEMS * 2);

    cvt_x_kernel<<<XB_ELEMS / (256 * 8), 256, 0, stream>>>(x, xb, wtp);
    scatter_kernel<<<(NNZ_ + 255) / 256, 256, 0, stream>>>(kv, idx, wtp);
    spconv_gemm<<<M_ / 96, 384, 0, stream>>>(xb, wtp, bias, out);
}

// Round 7
// 49.731 us; speedup vs baseline: 1.0678x; 1.0678x over previous
//
#include <hip/hip_runtime.h>

typedef unsigned short u16;
typedef __bf16 bf16x8 __attribute__((ext_vector_type(8)));
typedef float f32x4 __attribute__((ext_vector_type(4)));

#define B_   16
#define H_   56
#define W_   56
#define C_   128
#define OH_  54
#define OW_  54
#define NF_  256
#define KF_  1152           // C_*9
#define M_   46656          // B_*OH_*OW_
#define NNZ_ 58982

#define XB_ELEMS (B_*H_*W_*C_)       // 6422528
#define WT_ELEMS (36*4*256*8)        // 294912 (pre-tiled [kt][ks][col][8])

__device__ __forceinline__ u16 f2bf(float f) {
    unsigned u = __float_as_uint(f);
    u += 0x7FFFu + ((u >> 16) & 1u);
    return (u16)(u >> 16);
}

__device__ __forceinline__ void gload16(const void* g, void* l) {
    __builtin_amdgcn_global_load_lds(
        (const __attribute__((address_space(1))) unsigned int*)g,
        (__attribute__((address_space(3))) unsigned int*)l,
        16, 0, 0);
}

// ---- kernel 1: x f32 -> bf16 (8/thread) + fused zeroing of wt ----
__global__ __launch_bounds__(256) void cvt_x_kernel(const float* __restrict__ x,
                                                    u16* __restrict__ xb,
                                                    u16* __restrict__ wt) {
    // blocks 0..143 also zero the 576KB pre-tiled W image (144*256*16B exact)
    if (blockIdx.x < 144) {
        uint4 z = {0u, 0u, 0u, 0u};
        ((uint4*)wt)[blockIdx.x * 256 + threadIdx.x] = z;
    }
    int i = (blockIdx.x * 256 + threadIdx.x) * 8;
    float4 v0 = *(const float4*)(x + i);
    float4 v1 = *(const float4*)(x + i + 4);
    union { u16 u[8]; uint4 v; } r;
    r.u[0] = f2bf(v0.x); r.u[1] = f2bf(v0.y); r.u[2] = f2bf(v0.z); r.u[3] = f2bf(v0.w);
    r.u[4] = f2bf(v1.x); r.u[5] = f2bf(v1.y); r.u[6] = f2bf(v1.z); r.u[7] = f2bf(v1.w);
    *(uint4*)(xb + i) = r.v;
}

// ---- kernel 2: scatter sparse values into PRE-TILED W: [kt][ks][col][8] ----
__global__ __launch_bounds__(256) void scatter_kernel(const float* __restrict__ kv,
                                                      const int* __restrict__ idx,
                                                      u16* __restrict__ wt) {
    int t = blockIdx.x * 256 + threadIdx.x;
    if (t >= NNZ_) return;
    int k   = idx[2*t];      // row in [0,1152)
    int col = idx[2*t + 1];  // col in [0,256)
    int kt = k >> 5, ks = (k >> 3) & 3, e = k & 7;
    wt[(kt * 4 + ks) * 2048 + col * 8 + e] = f2bf(kv[t]);
}

// ---- kernel 3: implicit-GEMM conv, BM=64 x BN=128, max-TLP ----
// grid = 729*2 = 1458 blocks (5.7/CU), 4 waves, LDS 24KB (~5.7 blocks/CU
// resident -> ~23 waves/CU). 2-deep dbuf, counted vmcnt(3) (every thread
// stages exactly 1 A + 2 B gloads/tile; tile k+1 stays in flight).
// wg pairs (2m,2m+1) share A rows and land on the same XCD (b and b+8).
__global__ __launch_bounds__(256) void spconv_gemm(const u16* __restrict__ xb,
                                                   const u16* __restrict__ wt,
                                                   const float* __restrict__ bias,
                                                   float* __restrict__ out) {
    __shared__ __align__(16) u16 As[2][64 * 32];      // 2 x 4 KB
    __shared__ __align__(16) u16 Bs[2][4 * 128 * 8];  // 2 x 8 KB

    const int t    = threadIdx.x;
    const int lane = t & 63;
    const int wid  = t >> 6;

    // bijective XCD swizzle (nwg=1458 -> m204 formula)
    const int nwg = gridDim.x;
    const int q = nwg >> 3, r = nwg & 7;
    const int xcd = blockIdx.x & 7, inner = blockIdx.x >> 3;
    const int wg = (xcd < r ? xcd * (q + 1) : r * (q + 1) + (xcd - r) * q) + inner;
    const int mi = wg >> 1;           // 0..728
    const int ni = wg & 1;            // N half
    const int m0 = mi * 64;

    // A staging: thread t stages cell (arow = t>>2, kc = t&3); 4 lanes/row ->
    // 64B sectors. kc-XOR swizzle applied on the global SOURCE (linear dest).
    const int arow = t >> 2;
    const int kc   = t & 3;
    const int kcs  = kc ^ (arow & 3) ^ ((arow >> 2) & 3);
    const int kco  = kcs * 8;
    int mg  = m0 + arow;
    int bb  = mg / (OH_ * OW_);
    int rem = mg % (OH_ * OW_);
    int ii  = rem / OW_;
    int jj  = rem % OW_;
    const u16* a_base = xb + ((bb * H_ + ii) * W_ + jj) * C_;
    const int a_dst = t * 8;

    // B staging: thread t stages cells t and t+256 of the 512-cell half-tile.
    // Pre-tiled wt: [kt][ks][col][8]; our half = cols ni*128..+127 per ks ->
    // contiguous 1KB chunk at kt*8192 + ks*2048 + ni*1024.
    const u16* b_src0 = wt + (t >> 7) * 2048 + ni * 1024 + (t & 127) * 8;
    const u16* b_src1 = b_src0 + 2 * 2048;     // ks += 2
    const int b_dst0 = t * 8;
    const int b_dst1 = t * 8 + 2048;

    f32x4 acc[2][4];
    const f32x4 zz = {0.f, 0.f, 0.f, 0.f};
#pragma unroll
    for (int i = 0; i < 2; ++i)
#pragma unroll
        for (int j = 0; j < 4; ++j) acc[i][j] = zz;

    const int ks  = lane >> 4;
    const int r16 = lane & 15;
    const int cidx = ks ^ (r16 & 3) ^ ((r16 >> 2) & 3);
    const int wr = wid >> 1;          // 0..1  (M sub-block of 32)
    const int wc = wid & 1;           // 0..1  (N sub-block of 64)

#define ISSUE(kn, bi) do {                                                  \
    int g_  = (kn) >> 2;                                                    \
    int di_ = (g_ * 11) >> 5;                                               \
    int dj_ = g_ - 3 * di_;                                                 \
    int aoff_ = (di_ * W_ + dj_) * C_ + ((kn) & 3) * 32 + kco;              \
    gload16(a_base + aoff_, &As[bi][0] + a_dst);                            \
    gload16(b_src0 + (kn) * 8192, &Bs[bi][0] + b_dst0);                     \
    gload16(b_src1 + (kn) * 8192, &Bs[bi][0] + b_dst1);                     \
} while (0)

#define COMPUTE(bi) do {                                                    \
    bf16x8 a0_ = *(const bf16x8*)(&As[bi][(wr * 32 + r16) * 32 + cidx * 8]);\
    bf16x8 a1_ = *(const bf16x8*)(&As[bi][(wr * 32 + 16 + r16) * 32 + cidx * 8]); \
    _Pragma("unroll")                                                       \
    for (int nf = 0; nf < 4; ++nf) {                                        \
        bf16x8 b_ = *(const bf16x8*)(&Bs[bi][(ks * 128 + wc * 64 + nf * 16 + r16) * 8]); \
        acc[0][nf] = __builtin_amdgcn_mfma_f32_16x16x32_bf16(a0_, b_, acc[0][nf], 0, 0, 0); \
        acc[1][nf] = __builtin_amdgcn_mfma_f32_16x16x32_bf16(a1_, b_, acc[1][nf], 0, 0, 0); \
    }                                                                       \
} while (0)

// counted waits; "memory" clobber doubles as the compiler fence (rule #18
// analog, zero runtime cost). No sched_barrier pinning (m141 lesson).
#define WAITVM(n) asm volatile("s_waitcnt vmcnt(" #n ")" ::: "memory")
#define BAR() do { __builtin_amdgcn_s_barrier();                            \
                   asm volatile("" ::: "memory"); } while (0)

    // prologue: 2 tiles in flight (3 loads each, uniform across threads)
    ISSUE(0, 0);
    ISSUE(1, 1);

    // main loop: iters 0..33 issue tiles 2..35; vmcnt never drains to 0
#pragma unroll
    for (int k = 0; k < 34; ++k) {
        WAITVM(3);            // tile k landed; tile k+1's 3 loads in flight
        BAR();                // all waves' tile-k staging visible
        COMPUTE(k & 1);
        BAR();                // all waves done reading buf[k&1]
        ISSUE(k + 2, k & 1);
    }
    // tail: iters 34, 35
    WAITVM(3); BAR(); COMPUTE(0); BAR();
    WAITVM(0); BAR(); COMPUTE(1);

#undef ISSUE
#undef COMPUTE
#undef WAITVM
#undef BAR

    // epilogue: C/D layout col = lane&15, row = (lane>>4)*4 + reg (m89-verified)
    const int rgrp = lane >> 4;
#pragma unroll
    for (int nf = 0; nf < 4; ++nf) {
        int col  = ni * 128 + wc * 64 + nf * 16 + r16;
        float bv = bias[col];
#pragma unroll
        for (int mf = 0; mf < 2; ++mf) {
#pragma unroll
            for (int rr = 0; rr < 4; ++rr) {
                int row = m0 + wr * 32 + mf * 16 + rgrp * 4 + rr;
                float v = acc[mf][nf][rr] + bv;
                out[row * NF_ + col] = fmaxf(v, 0.f);
            }
        }
    }
}

extern "C" void kernel_launch(void* const* d_in, const int* in_sizes, int n_in,
                              void* d_out, int out_size, void* d_ws, size_t ws_size,
                              hipStream_t stream) {
    const float* x    = (const float*)d_in[0];
    const float* kv   = (const float*)d_in[1];
    const float* bias = (const float*)d_in[2];
    const int*   idx  = (const int*)d_in[3];
    float* out = (float*)d_out;

    u16* xb  = (u16*)d_ws;
    u16* wtp = (u16*)((char*)d_ws + (size_t)XB_ELEMS * 2);

    cvt_x_kernel<<<XB_ELEMS / (256 * 8), 256, 0, stream>>>(x, xb, wtp);
    scatter_kernel<<<(NNZ_ + 255) / 256, 256, 0, stream>>>(kv, idx, wtp);
    spconv_gemm<<<(M_ / 64) * 2, 256, 0, stream>>>(xb, wtp, bias, out);
}

// Round 8
// 45.664 us; speedup vs baseline: 1.1629x; 1.0891x over previous
//
#include <hip/hip_runtime.h>

typedef unsigned short u16;
typedef __bf16 bf16x8 __attribute__((ext_vector_type(8)));
typedef float f32x16 __attribute__((ext_vector_type(16)));

#define B_   16
#define H_   56
#define W_   56
#define C_   128
#define OH_  54
#define OW_  54
#define NF_  256
#define KF_  1152           // C_*9
#define M_   46656          // B_*OH_*OW_
#define NNZ_ 58982

#define XB_ELEMS (B_*H_*W_*C_)       // 6422528
#define WT_ELEMS (36*4*256*8)        // 294912 (pre-tiled [kt][ks][col][8])

__device__ __forceinline__ u16 f2bf(float f) {
    unsigned u = __float_as_uint(f);
    u += 0x7FFFu + ((u >> 16) & 1u);
    return (u16)(u >> 16);
}

__device__ __forceinline__ void gload16(const void* g, void* l) {
    __builtin_amdgcn_global_load_lds(
        (const __attribute__((address_space(1))) unsigned int*)g,
        (__attribute__((address_space(3))) unsigned int*)l,
        16, 0, 0);
}

// ---- kernel 1: x f32 -> bf16 (8/thread) + fused zeroing of wt ----
__global__ __launch_bounds__(256) void cvt_x_kernel(const float* __restrict__ x,
                                                    u16* __restrict__ xb,
                                                    u16* __restrict__ wt) {
    if (blockIdx.x < 144) {
        uint4 z = {0u, 0u, 0u, 0u};
        ((uint4*)wt)[blockIdx.x * 256 + threadIdx.x] = z;
    }
    int i = (blockIdx.x * 256 + threadIdx.x) * 8;
    float4 v0 = *(const float4*)(x + i);
    float4 v1 = *(const float4*)(x + i + 4);
    union { u16 u[8]; uint4 v; } r;
    r.u[0] = f2bf(v0.x); r.u[1] = f2bf(v0.y); r.u[2] = f2bf(v0.z); r.u[3] = f2bf(v0.w);
    r.u[4] = f2bf(v1.x); r.u[5] = f2bf(v1.y); r.u[6] = f2bf(v1.z); r.u[7] = f2bf(v1.w);
    *(uint4*)(xb + i) = r.v;
}

// ---- kernel 2: scatter sparse values into PRE-TILED W: [kt][ks][col][8] ----
__global__ __launch_bounds__(256) void scatter_kernel(const float* __restrict__ kv,
                                                      const int* __restrict__ idx,
                                                      u16* __restrict__ wt) {
    int t = blockIdx.x * 256 + threadIdx.x;
    if (t >= NNZ_) return;
    int k   = idx[2*t];      // row in [0,1152)
    int col = idx[2*t + 1];  // col in [0,256)
    int kt = k >> 5, ks = (k >> 3) & 3, e = k & 7;
    wt[(kt * 4 + ks) * 2048 + col * 8 + e] = f2bf(kv[t]);
}

// ---- kernel 3: B-in-registers implicit GEMM ----
// grid 729 (BM=64), 2 waves/block, wave tile 64x128 via mfma_32x32x16_bf16.
// A: LDS dbuf 2x4KB, layout [row][slot^(row&3)][8] (XOR on pre-swizzled
//    global source; gload_lds dest lane-linear).
// B: direct global->VGPR via inline-asm dwordx4 (coalesced from pre-tiled wt),
//    double-buffered regsets, deterministic vmcnt: 10 loads/tile (2 A + 8 B).
__global__ __launch_bounds__(128, 2) void spconv_gemm(const u16* __restrict__ xb,
                                                      const u16* __restrict__ wt,
                                                      const float* __restrict__ bias,
                                                      float* __restrict__ out) {
    __shared__ __align__(16) u16 As[2][64 * 32];   // 2 x 4 KB, [row][4 slots][8]

    const int t   = threadIdx.x;    // 0..127
    const int l   = t & 63;
    const int w   = t >> 6;         // wave id -> N half (cols w*128..)
    const int l31 = l & 31;
    const int hi  = l >> 5;

    // bijective XCD swizzle (nwg=729 -> m204 formula)
    const int nwg = gridDim.x;
    const int q = nwg >> 3, r = nwg & 7;
    const int xcd = blockIdx.x & 7, inner = blockIdx.x >> 3;
    const int wg = (xcd < r ? xcd * (q + 1) : r * (q + 1) + (xcd - r) * q) + inner;
    const int m0 = wg * 64;

    // ---- A staging setup: thread t stages cells t (row=t>>2) and t+128
    // (row=t>>2+32), slot t&3; source chunk = slot ^ (row&3) (read matches).
    const int row0 = t >> 2;
    const int kco  = ((t & 3) ^ ((t >> 2) & 3)) * 8;
    const u16* a_base0;
    const u16* a_base1;
    {
#define MKBASE(dst, mg) do {                                   \
        int bb_  = (mg) / (OH_ * OW_);                         \
        int rem_ = (mg) % (OH_ * OW_);                         \
        int ii_  = rem_ / OW_;                                 \
        int jj_  = rem_ % OW_;                                 \
        dst = xb + ((bb_ * H_ + ii_) * W_ + jj_) * C_;         \
    } while (0)
        MKBASE(a_base0, m0 + row0);
        MKBASE(a_base1, m0 + row0 + 32);
#undef MKBASE
    }

    // ---- B address setup (bytes). wt image [kt][ksi][col][8], 2B elems.
    // lane l, wave w, kstep p, colblk cb:
    //   byte = kt*16384 + (p*2 + hi)*4096 + (w*128 + cb*32 + l31)*16
    const char* wtb = (const char*)wt;
    const char* b0 = wtb + hi * 4096 + w * 2048 + l31 * 16;  // kstep 0
    const char* b1 = b0 + 8192;                               // kstep 1

    // ---- A read offsets (elems): [rb][kstep]
    int aoffr[2][2];
#pragma unroll
    for (int rb = 0; rb < 2; ++rb)
#pragma unroll
        for (int kp = 0; kp < 2; ++kp)
            aoffr[rb][kp] = ((rb * 32 + l31) * 4 + ((kp * 2 + hi) ^ (l & 3))) * 8;

    f32x16 acc[2][4];
#pragma unroll
    for (int i = 0; i < 2; ++i)
#pragma unroll
        for (int j = 0; j < 4; ++j) acc[i][j] = (f32x16)0.f;

    bf16x8 bS0[8], bS1[8];   // two B regsets (tile parity), [kstep*4 + cb]

#define LOADB(dst, base, imm) \
    asm volatile("global_load_dwordx4 %0, %1, off offset:" imm \
                 : "=v"(dst) : "v"(base) : "memory")

#define ISSUE_A(kn, bi) do {                                                \
    int g_  = (kn) >> 2;                                                    \
    int di_ = (g_ * 11) >> 5;                                               \
    int dj_ = g_ - 3 * di_;                                                 \
    int aoff_ = (di_ * W_ + dj_) * C_ + ((kn) & 3) * 32 + kco;              \
    gload16(a_base0 + aoff_, &As[bi][t * 8]);                               \
    gload16(a_base1 + aoff_, &As[bi][(t + 128) * 8]);                       \
} while (0)

#define ISSUE_B(bset) do {                                                  \
    LOADB(bset[0], b0, "0");    LOADB(bset[1], b0, "512");                  \
    LOADB(bset[2], b0, "1024"); LOADB(bset[3], b0, "1536");                 \
    LOADB(bset[4], b1, "0");    LOADB(bset[5], b1, "512");                  \
    LOADB(bset[6], b1, "1024"); LOADB(bset[7], b1, "1536");                 \
    b0 += 16384; b1 += 16384;                                               \
} while (0)

#define COMPUTE(bi, bset) do {                                              \
    bf16x8 af_[2][2];                                                       \
    _Pragma("unroll")                                                       \
    for (int rb = 0; rb < 2; ++rb)                                          \
        _Pragma("unroll")                                                   \
        for (int kp = 0; kp < 2; ++kp)                                      \
            af_[rb][kp] = *(const bf16x8*)(&As[bi][aoffr[rb][kp]]);         \
    _Pragma("unroll")                                                       \
    for (int kp = 0; kp < 2; ++kp)                                          \
        _Pragma("unroll")                                                   \
        for (int rb = 0; rb < 2; ++rb)                                      \
            _Pragma("unroll")                                               \
            for (int cb = 0; cb < 4; ++cb)                                  \
                acc[rb][cb] = __builtin_amdgcn_mfma_f32_32x32x16_bf16(      \
                    af_[rb][kp], bset[kp * 4 + cb], acc[rb][cb], 0, 0, 0);  \
} while (0)

#define WAITVM(n) asm volatile("s_waitcnt vmcnt(" #n ")" ::: "memory")
#define WAITLG0() asm volatile("s_waitcnt lgkmcnt(0)" ::: "memory")
#define SB0()     __builtin_amdgcn_sched_barrier(0)
#define BAR() do { __builtin_amdgcn_s_barrier();                            \
                   asm volatile("" ::: "memory"); } while (0)

    // prologue: tiles 0,1 in flight (10 vmem ops each: 2 A + 8 B)
    ISSUE_A(0, 0); ISSUE_B(bS0);
    ISSUE_A(1, 1); ISSUE_B(bS1);

    // main loop: pairs (k, k+1), k = 0,2,...,32; each half issues k+2
    for (int k2 = 0; k2 < 17; ++k2) {
        int kn0 = 2 * k2 + 2, kn1 = 2 * k2 + 3;
        WAITVM(10); SB0(); BAR();      // tile 2k2 landed (A in buf0, B in bS0)
        COMPUTE(0, bS0);
        WAITLG0(); BAR();              // A reads done -> buf0 reusable
        ISSUE_A(kn0, 0); ISSUE_B(bS0);
        WAITVM(10); SB0(); BAR();
        COMPUTE(1, bS1);
        WAITLG0(); BAR();
        ISSUE_A(kn1, 1); ISSUE_B(bS1);
    }
    // tail: tiles 34, 35
    WAITVM(10); SB0(); BAR(); COMPUTE(0, bS0);
    WAITVM(0);  SB0(); BAR(); COMPUTE(1, bS1);

#undef LOADB
#undef ISSUE_A
#undef ISSUE_B
#undef COMPUTE
#undef WAITVM
#undef WAITLG0
#undef SB0
#undef BAR

    // epilogue: 32x32 C/D layout col=lane&31, row=(reg&3)+8*(reg>>2)+4*(lane>>5)
#pragma unroll
    for (int cb = 0; cb < 4; ++cb) {
        int col  = w * 128 + cb * 32 + l31;
        float bv = bias[col];
#pragma unroll
        for (int rb = 0; rb < 2; ++rb) {
#pragma unroll
            for (int rg = 0; rg < 16; ++rg) {
                int row = m0 + rb * 32 + (rg & 3) + 8 * (rg >> 2) + 4 * hi;
                out[row * NF_ + col] = fmaxf(acc[rb][cb][rg] + bv, 0.f);
            }
        }
    }
}

extern "C" void kernel_launch(void* const* d_in, const int* in_sizes, int n_in,
                              void* d_out, int out_size, void* d_ws, size_t ws_size,
                              hipStream_t stream) {
    const float* x    = (const float*)d_in[0];
    const float* kv   = (const float*)d_in[1];
    const float* bias = (const float*)d_in[2];
    const int*   idx  = (const int*)d_in[3];
    float* out = (float*)d_out;

    u16* xb  = (u16*)d_ws;
    u16* wtp = (u16*)((char*)d_ws + (size_t)XB_ELEMS * 2);

    cvt_x_kernel<<<XB_ELEMS / (256 * 8), 256, 0, stream>>>(x, xb, wtp);
    scatter_kernel<<<(NNZ_ + 255) / 256, 256, 0, stream>>>(kv, idx, wtp);
    spconv_gemm<<<M_ / 64, 128, 0, stream>>>(xb, wtp, bias, out);
}